// Round 2
// baseline (58198.132 us; speedup 1.0000x reference)
//
#include <hip/hip_runtime.h>
#include <cstdint>
#include <cstddef>

typedef __attribute__((ext_vector_type(8))) short short8;   // 8 bf16 in 4 VGPRs
typedef __attribute__((ext_vector_type(4))) float f32x4;

#define HH     100
#define G4     400
#define BTOT   8192
#define TST    512
#define NOPSK  5
#define ROWS   32
#define NBLK   256
#define BLOCK  832          // 13 waves
#define NT     25           // 25 n-tiles of 16 -> 400
#define KT     3            // 3 k-tiles of 32 -> k<96
#define KRES   96           // residual k = 96..99 done in f32
#define HSTR   36           // f32 [k][r] col-major stride (words)
#define ASTR   104          // h_hi/h_lo row stride (bf16 elems); 208B, 16B-mult
#define TANHC  1.5f
#define EPSF   1e-9f

// precomputed once per launch by setup kernels
__device__ unsigned short d_Bhi[NT*KT*64*8];   // W_h hi, MFMA B-fragment order
__device__ unsigned short d_Blo[NT*KT*64*8];   // W_h lo residual
__device__ float d_Ep2[6*G4];                  // emb @ W_x  [e][n]
__device__ float d_Wres[G4*4];                 // W_h rows 96..99, [n][q]
__device__ float d_Z0t[(size_t)G4*BTOT];       // (x0 @ W_x)^T  [n][b], 13.1MB

static __device__ __forceinline__ unsigned short bf16hi(float f){
  unsigned u = __float_as_uint(f);
  return (unsigned short)((u + 0x7FFFu + ((u>>16)&1u)) >> 16);   // RNE
}
static __device__ __forceinline__ float bf16f(unsigned short s){
  return __uint_as_float(((unsigned)s)<<16);
}
static __device__ __forceinline__ float frcp(float x){ return __builtin_amdgcn_rcpf(x); }
static __device__ __forceinline__ float sigf(float x){ return frcp(1.0f + __expf(-x)); }
static __device__ __forceinline__ float tanh_f(float x){ return 1.0f - 2.0f*frcp(__expf(2.0f*x) + 1.0f); }

// ---- setup kernels -------------------------------------------------------

__global__ void setup_bpack(const float* __restrict__ Wh){
  int idx = blockIdx.x*blockDim.x + threadIdx.x;     // NT*KT*64 = 4800
  if (idx >= NT*KT*64) return;
  int nt = idx/(KT*64), rem = idx - nt*(KT*64), kt = rem>>6, ln = rem&63;
  int n = nt*16 + (ln & 15);
  #pragma unroll
  for (int i = 0; i < 8; ++i){
    int k = kt*32 + (ln>>4)*8 + i;                   // k < 96
    float w = Wh[k*G4 + n];
    unsigned short hi = bf16hi(w);
    unsigned short lo = bf16hi(w - bf16f(hi));
    d_Bhi[idx*8+i] = hi;
    d_Blo[idx*8+i] = lo;
  }
}

__global__ void setup_misc(const float* __restrict__ emb, const float* __restrict__ Wx,
                           const float* __restrict__ Wh){
  int idx = blockIdx.x*blockDim.x + threadIdx.x;     // 4000
  if (idx < 6*G4){
    int e = idx/G4, n = idx - e*G4;
    float s = 0.f;
    for (int k = 0; k < HH; ++k) s = fmaf(emb[e*HH+k], Wx[k*G4+n], s);
    d_Ep2[idx] = s;
  } else if (idx < 6*G4 + G4*4){
    int i = idx - 6*G4, n = i>>2, q = i&3;
    d_Wres[i] = Wh[(KRES+q)*G4 + n];
  }
}

__global__ void setup_z0(const float* __restrict__ x0, const float* __restrict__ Wx){
  int idx = blockIdx.x*blockDim.x + threadIdx.x;     // 8192 * 100
  int b = idx & (BTOT-1);
  int ng = idx >> 13;                                // 0..99 -> 4 n's
  f32x4 a = {0.f,0.f,0.f,0.f};
  for (int k = 0; k < HH; ++k){
    float x = x0[b*HH + k];
    f32x4 w = *(const f32x4*)&Wx[k*G4 + ng*4];
    a += w * x;
  }
  #pragma unroll
  for (int q = 0; q < 4; ++q) d_Z0t[(size_t)(ng*4+q)*BTOT + b] = a[q];
}

// ---- main persistent kernel ---------------------------------------------

__global__ __launch_bounds__(BLOCK) void rnn_main(
    const float* __restrict__ Wops, const float* __restrict__ u,
    float* __restrict__ out)
{
  __shared__ __align__(16) float z_lds[G4*HSTR];          // 57600 B  [n][r]
  __shared__ __align__(16) float h_lds[HH*HSTR];          // 14400 B  [k][r] f32
  __shared__ __align__(16) unsigned short h_hi[ROWS*ASTR];//  6656 B  [m][k] bf16
  __shared__ __align__(16) unsigned short h_lo[ROWS*ASTR];//  6656 B
  __shared__ __align__(16) float Ep2_l[6*G4];             //  9600 B
  __shared__ __align__(16) float Wres_l[G4*4];            //  6400 B
  __shared__ __align__(16) float Wops_l[HH*NOPSK];        //  2000 B
  __shared__ __align__(16) float red[800];                //  3200 B
  __shared__ int op_lds[ROWS];

  const int tid  = threadIdx.x;
  const int wave = tid >> 6;
  const int lane = tid & 63;
  const int cn   = lane & 15;        // n-offset (B,C) / m-row (A)
  const int q4   = lane >> 4;        // quad
  const int row0 = blockIdx.x * ROWS;
  const int nt0  = (wave < 12) ? wave*2 : 24;
  const int ntcnt= (wave < 12) ? 2 : 1;

  // prologue: stage constants, load B fragments into registers
  for (int i = tid; i < 6*G4;    i += BLOCK) Ep2_l[i]  = d_Ep2[i];
  for (int i = tid; i < G4*4;    i += BLOCK) Wres_l[i] = d_Wres[i];
  for (int i = tid; i < HH*NOPSK;i += BLOCK) Wops_l[i] = Wops[i];

  short8 bh[2][KT], bl[2][KT];
  {
    const short8* bph = (const short8*)d_Bhi;
    const short8* bpl = (const short8*)d_Blo;
    for (int ntl = 0; ntl < ntcnt; ++ntl)
      #pragma unroll
      for (int kt = 0; kt < KT; ++kt){
        int fi = ((nt0+ntl)*KT + kt)*64 + lane;
        bh[ntl][kt] = bph[fi];
        bl[ntl][kt] = bpl[fi];
      }
  }
  __syncthreads();

  float c_st[4] = {0.f,0.f,0.f,0.f};
  float lp_acc = 0.f, ent_acc = 0.f;
  float uv[NOPSK];

  for (int t = 0; t < TST; ++t){
    // ---- phase G: z_lds[n][r] for this block's 32 rows ----
    if (t == 0){
      for (int ntl = 0; ntl < ntcnt; ++ntl){
        int n = (nt0+ntl)*16 + cn;
        const float* zp = &d_Z0t[(size_t)n*BTOT + row0];
        #pragma unroll
        for (int mt = 0; mt < 2; ++mt){
          f32x4 v = *(const f32x4*)&zp[mt*16 + q4*4];
          *(f32x4*)&z_lds[n*HSTR + mt*16 + q4*4] = v;
        }
      }
    } else {
      #pragma unroll
      for (int mt = 0; mt < 2; ++mt){
        short8 ah[KT], al[KT];
        const int arow = (mt*16 + cn)*ASTR + q4*8;
        #pragma unroll
        for (int kt = 0; kt < KT; ++kt){
          ah[kt] = *(const short8*)&h_hi[arow + kt*32];
          al[kt] = *(const short8*)&h_lo[arow + kt*32];
        }
        for (int ntl = 0; ntl < ntcnt; ++ntl){
          int n = (nt0+ntl)*16 + cn;
          f32x4 acc = {0.f,0.f,0.f,0.f};
          #pragma unroll
          for (int kt = 0; kt < KT; ++kt){
            acc = __builtin_amdgcn_mfma_f32_16x16x32_bf16(ah[kt], bh[ntl][kt], acc, 0,0,0);
            acc = __builtin_amdgcn_mfma_f32_16x16x32_bf16(al[kt], bh[ntl][kt], acc, 0,0,0);
            acc = __builtin_amdgcn_mfma_f32_16x16x32_bf16(ah[kt], bl[ntl][kt], acc, 0,0,0);
          }
          f32x4 wr = *(const f32x4*)&Wres_l[n*4];         // k=96..99 residual, f32
          #pragma unroll
          for (int q = 0; q < 4; ++q){
            f32x4 hq = *(const f32x4*)&h_lds[(KRES+q)*HSTR + mt*16 + q4*4];
            acc += hq * wr[q];
          }
          *(f32x4*)&z_lds[n*HSTR + mt*16 + q4*4] = acc;
        }
      }
    }
    __syncthreads();   // b1: z ready; op_{t-1} (written post-b3 last step) ready

    // ---- phase E: u prefetch + elementwise LSTM ----
    if (tid >= 768 && tid < 800){
      int r = tid - 768;
      const float* up = u + ((size_t)t*BTOT + row0 + r)*NOPSK;
      #pragma unroll
      for (int o = 0; o < NOPSK; ++o) uv[o] = up[o];
    }
    if (tid < 800){
      const int je = tid >> 3, rg = tid & 7, r4e = rg*4;
      f32x4 z0 = *(const f32x4*)&z_lds[( 0 + je)*HSTR + r4e];
      f32x4 z1 = *(const f32x4*)&z_lds[(100 + je)*HSTR + r4e];
      f32x4 z2 = *(const f32x4*)&z_lds[(200 + je)*HSTR + r4e];
      f32x4 z3 = *(const f32x4*)&z_lds[(300 + je)*HSTR + r4e];
      if (t > 0){
        #pragma unroll
        for (int rr = 0; rr < 4; ++rr){
          int op = op_lds[r4e + rr];
          const float* ep = &Ep2_l[op*G4 + je];
          z0[rr] += ep[0]; z1[rr] += ep[100]; z2[rr] += ep[200]; z3[rr] += ep[300];
        }
      }
      f32x4 hv;
      #pragma unroll
      for (int rr = 0; rr < 4; ++rr){
        float cn_ = sigf(z1[rr])*c_st[rr] + sigf(z0[rr])*tanh_f(z2[rr]);
        c_st[rr] = cn_;
        hv[rr] = sigf(z3[rr])*tanh_f(cn_);
      }
      *(f32x4*)&h_lds[je*HSTR + r4e] = hv;
    }
    __syncthreads();   // b2: h_{t+1} in h_lds

    // ---- phase L: logits partials; phase S: bf16 split of h ----
    if (tid < 800){
      int rl = tid/25, rem = tid - rl*25, ol = rem/5, jql = rem - ol*5;
      float s = 0.f;
      #pragma unroll 4
      for (int jj = 0; jj < 20; ++jj){
        int j2 = jql*20 + jj;
        s = fmaf(h_lds[j2*HSTR + rl], Wops_l[j2*NOPSK + ol], s);
      }
      red[tid] = s;
    }
    if (tid < 768){
      int k = tid >> 3, rg = tid & 7;                    // k<96
      f32x4 hq = *(const f32x4*)&h_lds[k*HSTR + rg*4];
      #pragma unroll
      for (int q = 0; q < 4; ++q){
        unsigned short hi = bf16hi(hq[q]);
        unsigned short lo = bf16hi(hq[q] - bf16f(hi));
        h_hi[(rg*4+q)*ASTR + k] = hi;
        h_lo[(rg*4+q)*ASTR + k] = lo;
      }
    }
    __syncthreads();   // b3: red + h_hi/h_lo ready

    // ---- phase A: per-row sampling (wave 12, light GEMM load) ----
    if (tid >= 768 && tid < 800){
      int r = tid - 768;
      float l[NOPSK];
      #pragma unroll
      for (int o = 0; o < NOPSK; ++o){
        const float* rp = &red[r*25 + o*5];
        float s = (((rp[0]+rp[1])+rp[2])+rp[3])+rp[4];
        l[o] = TANHC * tanhf(s);                         // precise: only 32 threads
      }
      int op = 0; float best = -1e30f;
      #pragma unroll
      for (int o = 0; o < NOPSK; ++o){
        float gn = -logf(-logf(uv[o] + EPSF) + EPSF);    // precise libm
        float v = l[o] + gn;
        if (v > best){ best = v; op = o; }               // strict >: first-max ties
      }
      float m = l[0];
      #pragma unroll
      for (int o = 1; o < NOPSK; ++o) m = fmaxf(m, l[o]);
      float se = 0.f;
      #pragma unroll
      for (int o = 0; o < NOPSK; ++o) se += expf(l[o] - m);
      float lse = m + logf(se);
      float cur = lse - l[op];
      lp_acc  += cur;
      ent_acc += cur * expf(-cur);
      op_lds[r] = op;
      out[2*BTOT + (size_t)t*BTOT + row0 + r] = (float)op;
    }
    // no barrier: next phase G touches only z_lds/h_hi/h_lo (safe);
    // op_lds read is protected by next b1.
  }

  if (tid >= 768 && tid < 800){
    int r = tid - 768;
    out[row0 + r]        = lp_acc;
    out[BTOT + row0 + r] = ent_acc;
  }
}

extern "C" void kernel_launch(void* const* d_in, const int* in_sizes, int n_in,
                              void* d_out, int out_size, void* d_ws, size_t ws_size,
                              hipStream_t stream) {
  const float* x0   = (const float*)d_in[0];
  const float* Wx   = (const float*)d_in[1];
  const float* Wh   = (const float*)d_in[2];
  const float* Wops = (const float*)d_in[3];
  const float* emb  = (const float*)d_in[4];
  const float* u    = (const float*)d_in[5];
  (void)d_ws; (void)ws_size; (void)in_sizes; (void)n_in;

  setup_bpack<<<(NT*KT*64 + 255)/256, 256, 0, stream>>>(Wh);
  setup_misc<<<(6*G4 + G4*4 + 255)/256, 256, 0, stream>>>(emb, Wx, Wh);
  setup_z0<<<(BTOT*HH)/256, 256, 0, stream>>>(x0, Wx);
  rnn_main<<<NBLK, BLOCK, 0, stream>>>(Wops, u, (float*)d_out);
}

// Round 3
// 3086.621 us; speedup vs baseline: 18.8550x; 18.8550x over previous
//
#include <hip/hip_runtime.h>
#include <cstdint>
#include <cstddef>

typedef __attribute__((ext_vector_type(8))) short short8;   // 8 bf16 in 4 VGPRs
typedef __attribute__((ext_vector_type(4))) float f32x4;

#define HH     100
#define G4     400
#define BTOT   8192
#define TST    512
#define NOPSK  5
#define ROWS   32
#define NBLK   256
#define BLOCK  832          // 13 waves
#define NT     25           // 25 n-tiles of 16 -> 400
#define KT     3            // 3 k-tiles of 32 -> k<96
#define KRES   96           // residual k = 96..99 done in f32
#define HSTR   36           // f32 [k][r] col-major stride (words)
#define ASTR   104          // h_hi/h_lo row stride (bf16 elems); 208B, 16B-mult
#define TANHC  1.5f
#define EPSF   1e-9f

// precomputed once per launch by setup kernels
__device__ unsigned short d_Bhi[NT*KT*64*8];   // W_h hi, MFMA B-fragment order
__device__ unsigned short d_Blo[NT*KT*64*8];   // W_h lo residual
__device__ float d_Ep2[6*G4];                  // emb @ W_x  [e][n]
__device__ float d_Wres[G4*4];                 // W_h rows 96..99, [n][q]
__device__ float d_Z0t[(size_t)G4*BTOT];       // (x0 @ W_x)^T  [n][b], 13.1MB

static __device__ __forceinline__ unsigned short bf16hi(float f){
  unsigned u = __float_as_uint(f);
  return (unsigned short)((u + 0x7FFFu + ((u>>16)&1u)) >> 16);   // RNE
}
static __device__ __forceinline__ float bf16f(unsigned short s){
  return __uint_as_float(((unsigned)s)<<16);
}
static __device__ __forceinline__ float frcp(float x){ return __builtin_amdgcn_rcpf(x); }
static __device__ __forceinline__ float sigf(float x){ return frcp(1.0f + __expf(-x)); }
static __device__ __forceinline__ float tanh_f(float x){ return 1.0f - 2.0f*frcp(__expf(2.0f*x) + 1.0f); }

// ---- setup kernels -------------------------------------------------------

__global__ void setup_bpack(const float* __restrict__ Wh){
  int idx = blockIdx.x*blockDim.x + threadIdx.x;     // NT*KT*64 = 4800
  if (idx >= NT*KT*64) return;
  int nt = idx/(KT*64), rem = idx - nt*(KT*64), kt = rem>>6, ln = rem&63;
  int n = nt*16 + (ln & 15);
  #pragma unroll
  for (int i = 0; i < 8; ++i){
    int k = kt*32 + (ln>>4)*8 + i;                   // k < 96
    float w = Wh[k*G4 + n];
    unsigned short hi = bf16hi(w);
    unsigned short lo = bf16hi(w - bf16f(hi));
    d_Bhi[idx*8+i] = hi;
    d_Blo[idx*8+i] = lo;
  }
}

__global__ void setup_misc(const float* __restrict__ emb, const float* __restrict__ Wx,
                           const float* __restrict__ Wh){
  int idx = blockIdx.x*blockDim.x + threadIdx.x;     // 4000
  if (idx < 6*G4){
    int e = idx/G4, n = idx - e*G4;
    float s = 0.f;
    for (int k = 0; k < HH; ++k) s = fmaf(emb[e*HH+k], Wx[k*G4+n], s);
    d_Ep2[idx] = s;
  } else if (idx < 6*G4 + G4*4){
    int i = idx - 6*G4, n = i>>2, q = i&3;
    d_Wres[i] = Wh[(KRES+q)*G4 + n];
  }
}

// LDS-staged coalesced Z0 = x0 @ W_x, stored transposed [n][b]
__global__ __launch_bounds__(256) void setup_z0(const float* __restrict__ x0,
                                                const float* __restrict__ Wx){
  __shared__ float xs[64*101];                       // stride 101: conflict-free
  const int bb = blockIdx.x * 64;                    // 128 blocks
  for (int i = threadIdx.x; i < 64*HH; i += 256){
    int r = i/HH, k = i - r*HH;
    xs[r*101 + k] = x0[(size_t)(bb + r)*HH + k];     // coalesced global read
  }
  __syncthreads();
  const int bl = threadIdx.x & 63;
  for (int ng = threadIdx.x >> 6; ng < HH; ng += 4){ // 25 per thread
    f32x4 a = {0.f,0.f,0.f,0.f};
    for (int k = 0; k < HH; ++k){
      f32x4 w = *(const f32x4*)&Wx[k*G4 + ng*4];     // wave-uniform
      a += w * xs[bl*101 + k];
    }
    #pragma unroll
    for (int q = 0; q < 4; ++q)
      d_Z0t[(size_t)(ng*4+q)*BTOT + bb + bl] = a[q]; // coalesced per q
  }
}

// ---- main persistent kernel ---------------------------------------------

__global__ __launch_bounds__(BLOCK) void rnn_main(
    const float* __restrict__ Wops, const float* __restrict__ u,
    float* __restrict__ out)
{
  __shared__ __align__(16) float z_lds[G4*HSTR];          // 57600 B  [n][r]
  __shared__ __align__(16) float h_lds[HH*HSTR];          // 14400 B  [k][r] f32
  __shared__ __align__(16) unsigned short h_hi[ROWS*ASTR];//  6656 B  [m][k] bf16
  __shared__ __align__(16) unsigned short h_lo[ROWS*ASTR];//  6656 B
  __shared__ __align__(16) float Ep2_l[6*G4];             //  9600 B
  __shared__ __align__(16) float Wres_l[G4*4];            //  6400 B
  __shared__ __align__(16) float Wops_l[HH*NOPSK];        //  2000 B
  __shared__ __align__(16) float red[800];                //  3200 B
  __shared__ int op_lds[ROWS];

  const int tid  = threadIdx.x;
  const int wave = tid >> 6;
  const int lane = tid & 63;
  const int cn   = lane & 15;        // n-offset (B,C) / m-row (A)
  const int q4   = lane >> 4;        // quad
  const int row0 = blockIdx.x * ROWS;
  const int nt0  = (wave < 12) ? wave*2 : 24;
  const bool two = (wave < 12);      // wave-uniform: does this wave own 2 tiles?
  const int ntA[2] = { nt0, two ? nt0+1 : 24 };   // clamped (loads stay in-bounds)

  // prologue: stage constants, load B fragments into registers
  for (int i = tid; i < 6*G4;    i += BLOCK) Ep2_l[i]  = d_Ep2[i];
  for (int i = tid; i < G4*4;    i += BLOCK) Wres_l[i] = d_Wres[i];
  for (int i = tid; i < HH*NOPSK;i += BLOCK) Wops_l[i] = Wops[i];

  short8 bh[2][KT], bl[2][KT];
  {
    const short8* bph = (const short8*)d_Bhi;
    const short8* bpl = (const short8*)d_Blo;
    #pragma unroll
    for (int ntl = 0; ntl < 2; ++ntl)
      #pragma unroll
      for (int kt = 0; kt < KT; ++kt){
        int fi = (ntA[ntl]*KT + kt)*64 + lane;
        bh[ntl][kt] = bph[fi];
        bl[ntl][kt] = bpl[fi];
      }
  }
  __syncthreads();

  float c_st[4] = {0.f,0.f,0.f,0.f};
  float lp_acc = 0.f, ent_acc = 0.f;
  float uv[NOPSK];

  for (int t = 0; t < TST; ++t){
    // ---- phase G: z_lds[n][r] for this block's 32 rows ----
    if (t == 0){
      #pragma unroll
      for (int ntl = 0; ntl < 2; ++ntl){
        if (ntl == 0 || two){
          int n = ntA[ntl]*16 + cn;
          const float* zp = &d_Z0t[(size_t)n*BTOT + row0];
          #pragma unroll
          for (int mt = 0; mt < 2; ++mt){
            f32x4 v = *(const f32x4*)&zp[mt*16 + q4*4];
            *(f32x4*)&z_lds[n*HSTR + mt*16 + q4*4] = v;
          }
        }
      }
    } else {
      #pragma unroll
      for (int mt = 0; mt < 2; ++mt){
        short8 ah[KT], al[KT];
        const int arow = (mt*16 + cn)*ASTR + q4*8;
        #pragma unroll
        for (int kt = 0; kt < KT; ++kt){
          ah[kt] = *(const short8*)&h_hi[arow + kt*32];
          al[kt] = *(const short8*)&h_lo[arow + kt*32];
        }
        #pragma unroll
        for (int ntl = 0; ntl < 2; ++ntl){
          if (ntl == 0 || two){                          // wave-uniform guard
            const int n = ntA[ntl]*16 + cn;
            f32x4 acc = {0.f,0.f,0.f,0.f};
            #pragma unroll
            for (int kt = 0; kt < KT; ++kt){
              acc = __builtin_amdgcn_mfma_f32_16x16x32_bf16(ah[kt], bh[ntl][kt], acc, 0,0,0);
              acc = __builtin_amdgcn_mfma_f32_16x16x32_bf16(al[kt], bh[ntl][kt], acc, 0,0,0);
              acc = __builtin_amdgcn_mfma_f32_16x16x32_bf16(ah[kt], bl[ntl][kt], acc, 0,0,0);
            }
            f32x4 wr = *(const f32x4*)&Wres_l[n*4];      // k=96..99 residual, f32
            #pragma unroll
            for (int q = 0; q < 4; ++q){
              f32x4 hq = *(const f32x4*)&h_lds[(KRES+q)*HSTR + mt*16 + q4*4];
              acc += hq * wr[q];
            }
            *(f32x4*)&z_lds[n*HSTR + mt*16 + q4*4] = acc;
          }
        }
      }
    }
    __syncthreads();   // b1: z ready; op_{t-1} (written post-b3 last step) ready

    // ---- phase E: u prefetch + elementwise LSTM ----
    if (tid >= 768 && tid < 800){
      int r = tid - 768;
      const float* up = u + ((size_t)t*BTOT + row0 + r)*NOPSK;
      #pragma unroll
      for (int o = 0; o < NOPSK; ++o) uv[o] = up[o];
    }
    if (tid < 800){
      const int je = tid >> 3, rg = tid & 7, r4e = rg*4;
      f32x4 z0 = *(const f32x4*)&z_lds[( 0 + je)*HSTR + r4e];
      f32x4 z1 = *(const f32x4*)&z_lds[(100 + je)*HSTR + r4e];
      f32x4 z2 = *(const f32x4*)&z_lds[(200 + je)*HSTR + r4e];
      f32x4 z3 = *(const f32x4*)&z_lds[(300 + je)*HSTR + r4e];
      if (t > 0){
        #pragma unroll
        for (int rr = 0; rr < 4; ++rr){
          int op = op_lds[r4e + rr];
          const float* ep = &Ep2_l[op*G4 + je];
          z0[rr] += ep[0]; z1[rr] += ep[100]; z2[rr] += ep[200]; z3[rr] += ep[300];
        }
      }
      f32x4 hv;
      #pragma unroll
      for (int rr = 0; rr < 4; ++rr){
        float cn_ = sigf(z1[rr])*c_st[rr] + sigf(z0[rr])*tanh_f(z2[rr]);
        c_st[rr] = cn_;
        hv[rr] = sigf(z3[rr])*tanh_f(cn_);
      }
      *(f32x4*)&h_lds[je*HSTR + r4e] = hv;
    }
    __syncthreads();   // b2: h_{t+1} in h_lds

    // ---- phase L: logits partials; phase S: bf16 split of h ----
    if (tid < 800){
      int rl = tid/25, rem = tid - rl*25, ol = rem/5, jql = rem - ol*5;
      float s = 0.f;
      #pragma unroll 4
      for (int jj = 0; jj < 20; ++jj){
        int j2 = jql*20 + jj;
        s = fmaf(h_lds[j2*HSTR + rl], Wops_l[j2*NOPSK + ol], s);
      }
      red[tid] = s;
    }
    if (tid < 768){
      int k = tid >> 3, rg = tid & 7;                    // k<96
      f32x4 hq = *(const f32x4*)&h_lds[k*HSTR + rg*4];
      #pragma unroll
      for (int q = 0; q < 4; ++q){
        unsigned short hi = bf16hi(hq[q]);
        unsigned short lo = bf16hi(hq[q] - bf16f(hi));
        h_hi[(rg*4+q)*ASTR + k] = hi;
        h_lo[(rg*4+q)*ASTR + k] = lo;
      }
    }
    __syncthreads();   // b3: red + h_hi/h_lo ready

    // ---- phase A: per-row sampling (wave 12, light GEMM load) ----
    if (tid >= 768 && tid < 800){
      int r = tid - 768;
      float l[NOPSK];
      #pragma unroll
      for (int o = 0; o < NOPSK; ++o){
        const float* rp = &red[r*25 + o*5];
        float s = (((rp[0]+rp[1])+rp[2])+rp[3])+rp[4];
        l[o] = TANHC * tanhf(s);                         // precise: only 32 threads
      }
      int op = 0; float best = -1e30f;
      #pragma unroll
      for (int o = 0; o < NOPSK; ++o){
        float gn = -logf(-logf(uv[o] + EPSF) + EPSF);    // precise libm
        float v = l[o] + gn;
        if (v > best){ best = v; op = o; }               // strict >: first-max ties
      }
      float m = l[0];
      #pragma unroll
      for (int o = 1; o < NOPSK; ++o) m = fmaxf(m, l[o]);
      float se = 0.f;
      #pragma unroll
      for (int o = 0; o < NOPSK; ++o) se += expf(l[o] - m);
      float lse = m + logf(se);
      float cur = lse - l[op];
      lp_acc  += cur;
      ent_acc += cur * expf(-cur);
      op_lds[r] = op;
      out[2*BTOT + (size_t)t*BTOT + row0 + r] = (float)op;
    }
    // no barrier: next phase G touches only z_lds/h_hi/h_lo (safe);
    // op_lds read is protected by next b1.
  }

  if (tid >= 768 && tid < 800){
    int r = tid - 768;
    out[row0 + r]        = lp_acc;
    out[BTOT + row0 + r] = ent_acc;
  }
}

extern "C" void kernel_launch(void* const* d_in, const int* in_sizes, int n_in,
                              void* d_out, int out_size, void* d_ws, size_t ws_size,
                              hipStream_t stream) {
  const float* x0   = (const float*)d_in[0];
  const float* Wx   = (const float*)d_in[1];
  const float* Wh   = (const float*)d_in[2];
  const float* Wops = (const float*)d_in[3];
  const float* emb  = (const float*)d_in[4];
  const float* u    = (const float*)d_in[5];
  (void)d_ws; (void)ws_size; (void)in_sizes; (void)n_in;

  setup_bpack<<<(NT*KT*64 + 255)/256, 256, 0, stream>>>(Wh);
  setup_misc<<<(6*G4 + G4*4 + 255)/256, 256, 0, stream>>>(emb, Wx, Wh);
  setup_z0<<<BTOT/64, 256, 0, stream>>>(x0, Wx);
  rnn_main<<<NBLK, BLOCK, 0, stream>>>(Wops, u, (float*)d_out);
}

// Round 4
// 2421.510 us; speedup vs baseline: 24.0338x; 1.2747x over previous
//
#include <hip/hip_runtime.h>
#include <cstdint>
#include <cstddef>

typedef __attribute__((ext_vector_type(8))) short short8;   // 8 bf16 in 4 VGPRs
typedef __attribute__((ext_vector_type(4))) float f32x4;

#define HH     100
#define G4     400
#define BTOT   8192
#define TST    512
#define NOPSK  5
#define ROWS   32
#define NBLK   256
#define BLOCK  832          // 13 waves
#define NT     25           // 25 n-tiles of 16 -> 400
#define KT     3            // 3 k-tiles of 32 -> k<96
#define KRES   96           // residual k = 96..99 done in f32
#define HSTR   36           // f32 [k][r] col-major stride (words)
#define ASTR   104          // h_hi/h_lo row stride (bf16 elems); 208B, 16B-mult
#define TANHC  1.5f
#define EPSF   1e-9f

// precomputed once per launch by setup kernels
__device__ unsigned short d_Bhi[NT*KT*64*8];   // W_h hi, MFMA B-fragment order
__device__ unsigned short d_Blo[NT*KT*64*8];   // W_h lo residual
__device__ float d_Ep2[6*G4];                  // emb @ W_x  [e][je][g]
__device__ float d_Wres[G4*4];                 // W_h rows 96..99, [n][q]
__device__ float d_Z0t[(size_t)G4*BTOT];       // (x0 @ W_x)^T  [n][b], 13.1MB

static __device__ __forceinline__ unsigned short bf16hi(float f){
  unsigned u = __float_as_uint(f);
  return (unsigned short)((u + 0x7FFFu + ((u>>16)&1u)) >> 16);   // RNE
}
static __device__ __forceinline__ float bf16f(unsigned short s){
  return __uint_as_float(((unsigned)s)<<16);
}
static __device__ __forceinline__ float frcp(float x){ return __builtin_amdgcn_rcpf(x); }
static __device__ __forceinline__ float sigf(float x){ return frcp(1.0f + __expf(-x)); }
static __device__ __forceinline__ float tanh_f(float x){ return 1.0f - 2.0f*frcp(__expf(2.0f*x) + 1.0f); }

// ---- setup kernels -------------------------------------------------------

__global__ void setup_bpack(const float* __restrict__ Wh){
  int idx = blockIdx.x*blockDim.x + threadIdx.x;     // NT*KT*64 = 4800
  if (idx >= NT*KT*64) return;
  int nt = idx/(KT*64), rem = idx - nt*(KT*64), kt = rem>>6, ln = rem&63;
  int n = nt*16 + (ln & 15);
  #pragma unroll
  for (int i = 0; i < 8; ++i){
    int k = kt*32 + (ln>>4)*8 + i;                   // k < 96
    float w = Wh[k*G4 + n];
    unsigned short hi = bf16hi(w);
    unsigned short lo = bf16hi(w - bf16f(hi));
    d_Bhi[idx*8+i] = hi;
    d_Blo[idx*8+i] = lo;
  }
}

__global__ void setup_misc(const float* __restrict__ emb, const float* __restrict__ Wx,
                           const float* __restrict__ Wh){
  int idx = blockIdx.x*blockDim.x + threadIdx.x;     // 4000
  if (idx < 6*G4){
    int e = idx/G4, r2 = idx - e*G4, je = r2>>2, g = r2&3;   // [e][je][g]
    float s = 0.f;
    for (int k = 0; k < HH; ++k) s = fmaf(emb[e*HH+k], Wx[k*G4 + g*HH + je], s);
    d_Ep2[idx] = s;
  } else if (idx < 6*G4 + G4*4){
    int i = idx - 6*G4, n = i>>2, q = i&3;
    d_Wres[i] = Wh[(KRES+q)*G4 + n];
  }
}

// LDS-staged coalesced Z0 = x0 @ W_x, stored transposed [n][b]
__global__ __launch_bounds__(256) void setup_z0(const float* __restrict__ x0,
                                                const float* __restrict__ Wx){
  __shared__ float xs[64*101];                       // stride 101: conflict-free
  const int bb = blockIdx.x * 64;                    // 128 blocks
  for (int i = threadIdx.x; i < 64*HH; i += 256){
    int r = i/HH, k = i - r*HH;
    xs[r*101 + k] = x0[(size_t)(bb + r)*HH + k];     // coalesced global read
  }
  __syncthreads();
  const int bl = threadIdx.x & 63;
  for (int ng = threadIdx.x >> 6; ng < HH; ng += 4){ // 25 per thread
    f32x4 a = {0.f,0.f,0.f,0.f};
    for (int k = 0; k < HH; ++k){
      f32x4 w = *(const f32x4*)&Wx[k*G4 + ng*4];     // wave-uniform
      a += w * xs[bl*101 + k];
    }
    #pragma unroll
    for (int q = 0; q < 4; ++q)
      d_Z0t[(size_t)(ng*4+q)*BTOT + bb + bl] = a[q]; // coalesced per q
  }
}

// ---- main persistent kernel ---------------------------------------------

__global__ __launch_bounds__(BLOCK) void rnn_main(
    const float* __restrict__ Wops, const float* __restrict__ u,
    float* __restrict__ out)
{
  __shared__ __align__(16) float z_lds[G4*HSTR];          // 57600 B  [n][r]
  __shared__ __align__(16) float h_lds[HH*HSTR];          // 14400 B  [k][r] f32
  __shared__ __align__(16) unsigned short h_hi[ROWS*ASTR];//  6656 B  [m][k] bf16
  __shared__ __align__(16) unsigned short h_lo[ROWS*ASTR];//  6656 B
  __shared__ __align__(16) float Ep2_l[6*G4];             //  9600 B  [e][je][g]
  __shared__ __align__(16) float Wres_l[G4*4];            //  6400 B
  __shared__ __align__(16) float Wops_l[HH*NOPSK];        //  2000 B
  __shared__ __align__(16) float red[800];                //  3200 B
  __shared__ __align__(16) float gn_lds[ROWS*NOPSK];      //   640 B
  __shared__ int op_lds[ROWS];

  const int tid  = threadIdx.x;
  const int wave = tid >> 6;
  const int lane = tid & 63;
  const int cn   = lane & 15;        // n-offset (B,C) / m-row (A)
  const int q4   = lane >> 4;        // quad
  const int row0 = blockIdx.x * ROWS;
  const int nt0  = (wave < 12) ? wave*2 : 24;
  const bool two = (wave < 12);      // wave-uniform: does this wave own 2 tiles?
  const int ntA[2] = { nt0, two ? nt0+1 : 24 };   // clamped (loads stay in-bounds)

  // prologue: stage constants, load B fragments into registers
  for (int i = tid; i < 6*G4;    i += BLOCK) Ep2_l[i]  = d_Ep2[i];
  for (int i = tid; i < G4*4;    i += BLOCK) Wres_l[i] = d_Wres[i];
  for (int i = tid; i < HH*NOPSK;i += BLOCK) Wops_l[i] = Wops[i];

  short8 bh[2][KT], bl[2][KT];
  {
    const short8* bph = (const short8*)d_Bhi;
    const short8* bpl = (const short8*)d_Blo;
    #pragma unroll
    for (int ntl = 0; ntl < 2; ++ntl)
      #pragma unroll
      for (int kt = 0; kt < KT; ++kt){
        int fi = (ntA[ntl]*KT + kt)*64 + lane;
        bh[ntl][kt] = bph[fi];
        bl[ntl][kt] = bpl[fi];
      }
  }
  __syncthreads();

  float c_st[4] = {0.f,0.f,0.f,0.f};
  float lp_acc = 0.f, ent_acc = 0.f;

  for (int t = 0; t < TST; ++t){
    // ---- phase G: z_lds[n][r] for this block's 32 rows ----
    if (t == 0){
      #pragma unroll
      for (int ntl = 0; ntl < 2; ++ntl){
        if (ntl == 0 || two){
          int n = ntA[ntl]*16 + cn;
          const float* zp = &d_Z0t[(size_t)n*BTOT + row0];
          #pragma unroll
          for (int mt = 0; mt < 2; ++mt){
            f32x4 v = *(const f32x4*)&zp[mt*16 + q4*4];
            *(f32x4*)&z_lds[n*HSTR + mt*16 + q4*4] = v;
          }
        }
      }
    } else {
      #pragma unroll
      for (int mt = 0; mt < 2; ++mt){
        short8 ah[KT], al[KT];
        const int arow = (mt*16 + cn)*ASTR + q4*8;
        #pragma unroll
        for (int kt = 0; kt < KT; ++kt){
          ah[kt] = *(const short8*)&h_hi[arow + kt*32];
          al[kt] = *(const short8*)&h_lo[arow + kt*32];
        }
        #pragma unroll
        for (int ntl = 0; ntl < 2; ++ntl){
          if (ntl == 0 || two){                          // wave-uniform guard
            const int n = ntA[ntl]*16 + cn;
            f32x4 acc = {0.f,0.f,0.f,0.f};
            #pragma unroll
            for (int kt = 0; kt < KT; ++kt){
              acc = __builtin_amdgcn_mfma_f32_16x16x32_bf16(ah[kt], bh[ntl][kt], acc, 0,0,0);
              acc = __builtin_amdgcn_mfma_f32_16x16x32_bf16(al[kt], bh[ntl][kt], acc, 0,0,0);
              acc = __builtin_amdgcn_mfma_f32_16x16x32_bf16(ah[kt], bl[ntl][kt], acc, 0,0,0);
            }
            f32x4 wr = *(const f32x4*)&Wres_l[n*4];      // k=96..99 residual, f32
            #pragma unroll
            for (int q = 0; q < 4; ++q){
              f32x4 hq = *(const f32x4*)&h_lds[(KRES+q)*HSTR + mt*16 + q4*4];
              acc += hq * wr[q];
            }
            *(f32x4*)&z_lds[n*HSTR + mt*16 + q4*4] = acc;
          }
        }
      }
    }
    __syncthreads();   // b1: z ready; op_{t-1}/red/gn consumed by A before this

    // ---- phase E: LSTM elementwise + bf16 split (fused S) ----
    if (tid < 800){
      const int je = tid >> 3, rg = tid & 7, r4e = rg*4;
      f32x4 z0 = *(const f32x4*)&z_lds[( 0 + je)*HSTR + r4e];
      f32x4 z1 = *(const f32x4*)&z_lds[(100 + je)*HSTR + r4e];
      f32x4 z2 = *(const f32x4*)&z_lds[(200 + je)*HSTR + r4e];
      f32x4 z3 = *(const f32x4*)&z_lds[(300 + je)*HSTR + r4e];
      if (t > 0){
        #pragma unroll
        for (int rr = 0; rr < 4; ++rr){
          int op = op_lds[r4e + rr];
          f32x4 e4 = *(const f32x4*)&Ep2_l[op*G4 + je*4];   // [e][je][g] b128
          z0[rr] += e4.x; z1[rr] += e4.y; z2[rr] += e4.z; z3[rr] += e4.w;
        }
      }
      f32x4 hv;
      #pragma unroll
      for (int rr = 0; rr < 4; ++rr){
        float cn_ = sigf(z1[rr])*c_st[rr] + sigf(z0[rr])*tanh_f(z2[rr]);
        c_st[rr] = cn_;
        hv[rr] = sigf(z3[rr])*tanh_f(cn_);
      }
      *(f32x4*)&h_lds[je*HSTR + r4e] = hv;
      if (je < KRES){                                    // fused bf16 split
        #pragma unroll
        for (int q = 0; q < 4; ++q){
          unsigned short hi = bf16hi(hv[q]);
          unsigned short lo = bf16hi(hv[q] - bf16f(hi));
          h_hi[(r4e+q)*ASTR + je] = hi;
          h_lo[(r4e+q)*ASTR + je] = lo;
        }
      }
    } else {
      // ---- lanes 800..831: u load + gumbel noise (off A's critical path) ----
      int r = tid - 800;
      const float* up = u + ((size_t)t*BTOT + row0 + r)*NOPSK;
      #pragma unroll
      for (int o = 0; o < NOPSK; ++o){
        float uu = up[o];
        gn_lds[r*NOPSK + o] = -__logf(-__logf(uu + EPSF) + EPSF);
      }
    }
    __syncthreads();   // b2: h_{t+1} in h_lds, h_hi/h_lo, gn ready

    // ---- phase L: logits partials (conflict-free stride-5 interleave) ----
    if (tid < 800){
      int rl = tid/25, rem = tid - rl*25, ol = rem/5, jql = rem - ol*5;
      float s = 0.f;
      #pragma unroll 4
      for (int jj = 0; jj < 20; ++jj){
        int j2 = jql + 5*jj;                             // stride-5: no bank alias
        s = fmaf(h_lds[j2*HSTR + rl], Wops_l[j2*NOPSK + ol], s);
      }
      red[tid] = s;
    }
    __syncthreads();   // b3: red ready

    // ---- phase A: per-row sampling (hw transcendentals, ~1-2 ulp) ----
    if (tid >= 768 && tid < 800){
      int r = tid - 768;
      float l[NOPSK];
      #pragma unroll
      for (int o = 0; o < NOPSK; ++o){
        const float* rp = &red[r*25 + o*5];
        float s = (((rp[0]+rp[1])+rp[2])+rp[3])+rp[4];
        l[o] = TANHC * tanh_f(s);
      }
      int op = 0; float best = -1e30f;
      #pragma unroll
      for (int o = 0; o < NOPSK; ++o){
        float v = l[o] + gn_lds[r*NOPSK + o];
        if (v > best){ best = v; op = o; }               // strict >: first-max ties
      }
      float m = l[0];
      #pragma unroll
      for (int o = 1; o < NOPSK; ++o) m = fmaxf(m, l[o]);
      float se = 0.f;
      #pragma unroll
      for (int o = 0; o < NOPSK; ++o) se += __expf(l[o] - m);
      float lse = m + __logf(se);
      float cur = lse - l[op];
      lp_acc  += cur;
      ent_acc += cur * __expf(-cur);
      op_lds[r] = op;
      out[2*BTOT + (size_t)t*BTOT + row0 + r] = (float)op;
    }
    // no barrier: next G touches only z_lds/h_hi/h_lo; op_lds/red/gn reads
    // are protected by next b1 (no wave passes b1 until A's wave arrives).
  }

  if (tid >= 768 && tid < 800){
    int r = tid - 768;
    out[row0 + r]        = lp_acc;
    out[BTOT + row0 + r] = ent_acc;
  }
}

extern "C" void kernel_launch(void* const* d_in, const int* in_sizes, int n_in,
                              void* d_out, int out_size, void* d_ws, size_t ws_size,
                              hipStream_t stream) {
  const float* x0   = (const float*)d_in[0];
  const float* Wx   = (const float*)d_in[1];
  const float* Wh   = (const float*)d_in[2];
  const float* Wops = (const float*)d_in[3];
  const float* emb  = (const float*)d_in[4];
  const float* u    = (const float*)d_in[5];
  (void)d_ws; (void)ws_size; (void)in_sizes; (void)n_in;

  setup_bpack<<<(NT*KT*64 + 255)/256, 256, 0, stream>>>(Wh);
  setup_misc<<<(6*G4 + G4*4 + 255)/256, 256, 0, stream>>>(emb, Wx, Wh);
  setup_z0<<<BTOT/64, 256, 0, stream>>>(x0, Wx);
  rnn_main<<<NBLK, BLOCK, 0, stream>>>(Wops, u, (float*)d_out);
}